// Round 6
// baseline (39.951 us; speedup 1.0000x reference)
//
#include <hip/hip_runtime.h>
#include <math.h>

#define BB 4
#define RR 64
#define SS 512
#define HH 768
#define EE 64
#define SEGD 128
#define NT 6
#define NC 13
#define NP 3
#define NO (NT + NC + NP)        // 22
#define REP 2560                 // 2*H + 2*SEG + H
#define NEGV -1e30f

// ---- structure: lane = relation; uniform (scalar) loads of hidden+mask ----
#define NHC4 (HH / 4)            // 192 column-groups of 4
#define NSH  4                   // s-quarters
#define NB_CTX (BB * NHC4 * NSH) // 3072 blocks of 64 threads
#define NPK  32                  // pack blocks
#define NTB  64                  // W-transpose blocks
#define WT_ELEMS (REP * NO)      // 56320

// ws float offsets
#define CTXP_OFF 4096                          // after 16KB packed region
#define CTXP_ELEMS ((size_t)NSH * BB * RR * HH)  // 786432
#define WT_OFF (CTXP_OFF + CTXP_ELEMS)         // 790528

// ---------------- kernel 0: bit-pack masks (ballot) + W transpose ----------------
__global__ __launch_bounds__(256)
void p0_prep(const int* __restrict__ rel_masks,   // [B,R,S]
             const float* __restrict__ Wt,
             const float* __restrict__ Wc,
             const float* __restrict__ Wp,
             unsigned long long* __restrict__ packed,  // [B,S]
             float* __restrict__ WT)                   // [NO][REP]
{
    const int bid = blockIdx.x;
    const int t   = threadIdx.x;

    if (bid < NPK) {
        // pack: block (b, s-chunk of 64); wave w handles 16 s; lane = relation
        const int b    = bid >> 3;
        const int sc   = bid & 7;
        const int w    = t >> 6;
        const int lane = t & 63;
        const int sbase = sc * 64 + w * 16;
#pragma unroll
        for (int i = 0; i < 16; ++i) {
            const int s = sbase + i;
            const int mv = rel_masks[((size_t)b * RR + lane) * SS + s];
            const unsigned long long bal = __ballot(mv != 0);
            if (lane == 0) packed[(size_t)b * SS + s] = bal;
        }
    } else {
        // transpose three W matrices into WT[o][f]
        for (int e = (bid - NPK) * 256 + t; e < WT_ELEMS; e += NTB * 256) {
            const int o = e / REP;
            const int f = e - o * REP;
            float v;
            if (o < NT)           v = Wt[(size_t)f * NT + o];
            else if (o < NT + NC) v = Wc[(size_t)f * NC + (o - NT)];
            else                  v = Wp[(size_t)f * NP + (o - NT - NC)];
            WT[e] = v;
        }
    }
}

// ---------------- kernel 1: ctx masked-max, lane = relation, scalar loads ----------
__global__ __launch_bounds__(64)
void p1_ctx(const float* __restrict__ hidden,               // [B,S,H]
            const unsigned long long* __restrict__ packed,  // [B,S]
            float* __restrict__ ctxp)                       // [NSH][B*R][H]
{
    const int bid  = blockIdx.x;
    const int sh   = bid & 3;
    const int hc   = (bid >> 2) % NHC4;
    const int b    = bid / (4 * NHC4);
    const int lane = threadIdx.x;       // 0..63 = relation
    const int h    = hc * 4;
    const int s0   = sh * (SS / NSH);   // 128 rows per quarter

    const float* hp = hidden + ((size_t)b * SS + s0) * HH + h;
    const unsigned long long* pk = packed + (size_t)b * SS + s0;

    const unsigned int shl = 31 - (lane & 31);
    const bool hiword = (lane >= 32);

    float m0 = -INFINITY, m1 = -INFINITY, m2 = -INFINITY, m3 = -INFINITY;
#pragma unroll 8
    for (int s = 0; s < SS / NSH; ++s) {
        const unsigned long long w = pk[s];                  // uniform -> s_load
        const float4 v = *reinterpret_cast<const float4*>(hp + (size_t)s * HH); // uniform
        const unsigned int half = hiword ? (unsigned int)(w >> 32) : (unsigned int)w;
        const int sb = (int)(half << shl);                   // bit 'lane' -> sign bit
        const float a = (sb < 0) ? 0.f : NEGV;
        m0 = fmaxf(m0, v.x + a);
        m1 = fmaxf(m1, v.y + a);
        m2 = fmaxf(m2, v.z + a);
        m3 = fmaxf(m3, v.w + a);
    }

    *reinterpret_cast<float4*>(
        ctxp + (((size_t)sh * (BB * RR)) + (size_t)b * RR + lane) * HH + h) =
        make_float4(m0, m1, m2, m3);
}

// ---------------- kernel 2: reduce partials, gather, coalesced WT matvec ----------
__global__ __launch_bounds__(256)
void p2_head(const float* __restrict__ ws,          // ctx partials + WT
             const int*   __restrict__ rel_pairs,   // [B,R,2]
             const float* __restrict__ span,        // [B,E,H]
             const float* __restrict__ segs,        // [B,E,SEG]
             const float* __restrict__ bt,
             const float* __restrict__ bc,
             const float* __restrict__ bp,
             float* __restrict__ out)
{
    const int br = blockIdx.x;
    const int b  = br / RR;
    const int t  = threadIdx.x;

    __shared__ float feat[REP];
    __shared__ float red[4][NO];

    const int i0 = rel_pairs[(size_t)br * 2 + 0];
    const int i1 = rel_pairs[(size_t)br * 2 + 1];
    const int CTX0 = 2 * HH + 2 * SEGD;   // 1792

    if (t < 192) {
        // combine NSH partial maxes for this relation's ctx columns
        const float* cb = ws + CTXP_OFF + (size_t)br * HH + 4 * t;
        float4 mm = make_float4(-INFINITY, -INFINITY, -INFINITY, -INFINITY);
#pragma unroll
        for (int p = 0; p < NSH; ++p) {
            const float4 c = *reinterpret_cast<const float4*>(
                cb + (size_t)p * (BB * RR) * HH);
            mm.x = fmaxf(mm.x, c.x);
            mm.y = fmaxf(mm.y, c.y);
            mm.z = fmaxf(mm.z, c.z);
            mm.w = fmaxf(mm.w, c.w);
        }
        // all-masked rows collapse to ~-1e30; reference zeroes them
        if (mm.x < -1e29f) mm.x = 0.f;
        if (mm.y < -1e29f) mm.y = 0.f;
        if (mm.z < -1e29f) mm.z = 0.f;
        if (mm.w < -1e29f) mm.w = 0.f;
        *reinterpret_cast<float4*>(&feat[CTX0 + 4 * t]) = mm;
    } else {
        // gather span/seg embeddings: 448 float4s over 64 threads
        for (int k = t - 192; k < 448; k += 64) {
            float4 v; int dst;
            if (k < 192) {
                v = *reinterpret_cast<const float4*>(span + ((size_t)b * EE + i0) * HH + 4 * k);
                dst = 4 * k;
            } else if (k < 384) {
                const int u = k - 192;
                v = *reinterpret_cast<const float4*>(span + ((size_t)b * EE + i1) * HH + 4 * u);
                dst = HH + 4 * u;
            } else if (k < 416) {
                const int u = k - 384;
                v = *reinterpret_cast<const float4*>(segs + ((size_t)b * EE + i0) * SEGD + 4 * u);
                dst = 2 * HH + 4 * u;
            } else {
                const int u = k - 416;
                v = *reinterpret_cast<const float4*>(segs + ((size_t)b * EE + i1) * SEGD + 4 * u);
                dst = 2 * HH + SEGD + 4 * u;
            }
            *reinterpret_cast<float4*>(&feat[dst]) = v;
        }
    }
    __syncthreads();

    // matvec: thread t owns f = {4t, 4t+1024, 4t+2048(<REP)} as float4, WT coalesced
    const float* WT = ws + WT_OFF;
    const float4 f0 = *reinterpret_cast<const float4*>(&feat[4 * t]);
    const float4 f1 = *reinterpret_cast<const float4*>(&feat[4 * t + 1024]);
    const bool has2 = (t < 128);          // wave-uniform (waves 0,1)
    float4 f2 = make_float4(0.f, 0.f, 0.f, 0.f);
    if (has2) f2 = *reinterpret_cast<const float4*>(&feat[4 * t + 2048]);

    float acc[NO];
#pragma unroll 4
    for (int o = 0; o < NO; ++o) {
        const float* row = WT + (size_t)o * REP + 4 * t;
        const float4 w0 = *reinterpret_cast<const float4*>(row);
        const float4 w1 = *reinterpret_cast<const float4*>(row + 1024);
        float s = f0.x * w0.x + f0.y * w0.y + f0.z * w0.z + f0.w * w0.w
                + f1.x * w1.x + f1.y * w1.y + f1.z * w1.z + f1.w * w1.w;
        if (has2) {
            const float4 w2 = *reinterpret_cast<const float4*>(row + 2048);
            s += f2.x * w2.x + f2.y * w2.y + f2.z * w2.z + f2.w * w2.w;
        }
        acc[o] = s;
    }

#pragma unroll
    for (int o = 0; o < NO; ++o) {
#pragma unroll
        for (int off = 32; off > 0; off >>= 1)
            acc[o] += __shfl_down(acc[o], off, 64);
    }
    const int wid  = t >> 6;
    const int lane = t & 63;
    if (lane == 0) {
#pragma unroll
        for (int o = 0; o < NO; ++o) red[wid][o] = acc[o];
    }
    __syncthreads();

    if (t < NO) {
        const float v = red[0][t] + red[1][t] + red[2][t] + red[3][t];
        if (t < NT) {
            out[(size_t)br * NT + t] = v + bt[t];
        } else if (t < NT + NC) {
            const int o = t - NT;
            out[(size_t)BB * RR * NT + (size_t)br * NC + o] = v + bc[o];
        } else {
            const int o = t - NT - NC;
            out[(size_t)BB * RR * (NT + NC) + (size_t)br * NP + o] = v + bp[o];
        }
    }
}

// ---------------- fallback: fused single kernel (if ws too small) ----------------
__global__ __launch_bounds__(256)
void rel_cls_fused(const float* __restrict__ hidden,
                   const int*   __restrict__ rel_pairs,
                   const int*   __restrict__ rel_masks,
                   const float* __restrict__ span,
                   const float* __restrict__ segs,
                   const float* __restrict__ Wt, const float* __restrict__ bt,
                   const float* __restrict__ Wc, const float* __restrict__ bc,
                   const float* __restrict__ Wp, const float* __restrict__ bp,
                   float* __restrict__ out)
{
    const int br = blockIdx.x;
    const int b  = br / RR;
    const int t  = threadIdx.x;

    __shared__ float sadd[SS];
    __shared__ float feat[REP];
    __shared__ float red[4][NO];

    const int* mrow = rel_masks + (size_t)br * SS;
    sadd[t]       = mrow[t] ? 0.f : NEGV;
    sadd[t + 256] = mrow[t + 256] ? 0.f : NEGV;

    const int i0 = rel_pairs[(size_t)br * 2 + 0];
    const int i1 = rel_pairs[(size_t)br * 2 + 1];
    const float* sp0 = span + ((size_t)b * EE + i0) * HH;
    const float* sp1 = span + ((size_t)b * EE + i1) * HH;
    feat[t]            = sp0[t];
    feat[t + 256]      = sp0[t + 256];
    feat[t + 512]      = sp0[t + 512];
    feat[HH + t]       = sp1[t];
    feat[HH + t + 256] = sp1[t + 256];
    feat[HH + t + 512] = sp1[t + 512];
    const float* sg0 = segs + ((size_t)b * EE + i0) * SEGD;
    const float* sg1 = segs + ((size_t)b * EE + i1) * SEGD;
    if (t < SEGD) feat[2 * HH + t] = sg0[t];
    else          feat[2 * HH + SEGD + (t - SEGD)] = sg1[t - SEGD];
    __syncthreads();

    float m0 = -INFINITY, m1 = -INFINITY, m2 = -INFINITY;
#pragma unroll 8
    for (int s = 0; s < SS; ++s) {
        const float* hp = hidden + ((size_t)b * SS + s) * HH;
        const float a = sadd[s];
        m0 = fmaxf(m0, hp[t] + a);
        m1 = fmaxf(m1, hp[t + 256] + a);
        m2 = fmaxf(m2, hp[t + 512] + a);
    }
    if (m0 < -1e29f) m0 = 0.f;
    if (m1 < -1e29f) m1 = 0.f;
    if (m2 < -1e29f) m2 = 0.f;
    const int CTX0 = 2 * HH + 2 * SEGD;
    feat[CTX0 + t]       = m0;
    feat[CTX0 + t + 256] = m1;
    feat[CTX0 + t + 512] = m2;
    __syncthreads();

    float acc[NO];
#pragma unroll
    for (int o = 0; o < NO; ++o) acc[o] = 0.f;
    for (int f = t; f < REP; f += 256) {
        const float fv = feat[f];
        const float* wt = Wt + (size_t)f * NT;
        const float* wc = Wc + (size_t)f * NC;
        const float* wp = Wp + (size_t)f * NP;
#pragma unroll
        for (int o = 0; o < NT; ++o) acc[o]           += fv * wt[o];
#pragma unroll
        for (int o = 0; o < NC; ++o) acc[NT + o]      += fv * wc[o];
#pragma unroll
        for (int o = 0; o < NP; ++o) acc[NT + NC + o] += fv * wp[o];
    }
#pragma unroll
    for (int o = 0; o < NO; ++o) {
#pragma unroll
        for (int off = 32; off > 0; off >>= 1)
            acc[o] += __shfl_down(acc[o], off, 64);
    }
    const int wid  = t >> 6;
    const int lane = t & 63;
    if (lane == 0) {
#pragma unroll
        for (int o = 0; o < NO; ++o) red[wid][o] = acc[o];
    }
    __syncthreads();

    if (t < NO) {
        const float v = red[0][t] + red[1][t] + red[2][t] + red[3][t];
        if (t < NT) {
            out[(size_t)br * NT + t] = v + bt[t];
        } else if (t < NT + NC) {
            const int o = t - NT;
            out[(size_t)BB * RR * NT + (size_t)br * NC + o] = v + bc[o];
        } else {
            const int o = t - NT - NC;
            out[(size_t)BB * RR * (NT + NC) + (size_t)br * NP + o] = v + bp[o];
        }
    }
}

extern "C" void kernel_launch(void* const* d_in, const int* in_sizes, int n_in,
                              void* d_out, int out_size, void* d_ws, size_t ws_size,
                              hipStream_t stream) {
    const float* hidden = (const float*)d_in[0];
    const int*   pairs  = (const int*)d_in[1];
    const int*   masks  = (const int*)d_in[2];
    const float* span   = (const float*)d_in[4];
    const float* segs   = (const float*)d_in[5];
    const float* Wt     = (const float*)d_in[6];
    const float* bt     = (const float*)d_in[7];
    const float* Wc     = (const float*)d_in[8];
    const float* bc     = (const float*)d_in[9];
    const float* Wp     = (const float*)d_in[10];
    const float* bp     = (const float*)d_in[11];
    float* out = (float*)d_out;
    float* ws  = (float*)d_ws;

    const size_t need = (WT_OFF + (size_t)WT_ELEMS) * sizeof(float);  // ~3.4 MB

    if (ws_size >= need) {
        unsigned long long* packed = (unsigned long long*)d_ws;  // first 16 KB
        float* ctxp = ws + CTXP_OFF;
        float* WT   = ws + WT_OFF;

        hipLaunchKernelGGL(p0_prep, dim3(NPK + NTB), dim3(256), 0, stream,
                           masks, Wt, Wc, Wp, packed, WT);
        hipLaunchKernelGGL(p1_ctx, dim3(NB_CTX), dim3(64), 0, stream,
                           hidden, packed, ctxp);
        hipLaunchKernelGGL(p2_head, dim3(BB * RR), dim3(256), 0, stream,
                           ws, pairs, span, segs, bt, bc, bp, out);
    } else {
        hipLaunchKernelGGL(rel_cls_fused, dim3(BB * RR), dim3(256), 0, stream,
                           hidden, pairs, masks, span, segs,
                           Wt, bt, Wc, bc, Wp, bp, out);
    }
}